// Round 1
// baseline (282.804 us; speedup 1.0000x reference)
//
#include <hip/hip_runtime.h>
#include <hip/hip_bf16.h>

#define NSP 4096   // H*W
#define CCH 256    // C
#define CIN 128    // Ci
#define NBATCH 4
#define BN_EPS 1e-5f

// ---------------- tile helpers: 64x64 block tile, BK=16, 16x16 threads, 4x4 micro ----

// transpose-load: A row-major (lda), rows m0..m0+63, cols k0..k0+15 -> As[k][m]
__device__ __forceinline__ void load_tr(const float* __restrict__ A, int lda, int m0, int k0,
                                        float (*As)[68], int tid) {
  const int r = tid >> 2;            // 0..63
  const int kq = (tid & 3) << 2;     // 0,4,8,12
  const float4 v = *(const float4*)(A + (size_t)(m0 + r) * lda + k0 + kq);
  As[kq + 0][r] = v.x;
  As[kq + 1][r] = v.y;
  As[kq + 2][r] = v.z;
  As[kq + 3][r] = v.w;
}

// direct-load: B row-major (ldb), rows k0..k0+15, cols n0..n0+63 -> Bs[k][n]
__device__ __forceinline__ void load_dir(const float* __restrict__ B, int ldb, int k0, int n0,
                                         float (*Bs)[68], int tid) {
  const int kr = tid >> 4;           // 0..15
  const int nq = (tid & 15) << 2;    // 0..60
  const float4 v = *(const float4*)(B + (size_t)(k0 + kr) * ldb + n0 + nq);
  *(float4*)(&Bs[kr][nq]) = v;       // stride 68 keeps 16B alignment
}

__device__ __forceinline__ void mm16(const float (*As)[68], const float (*Bs)[68],
                                     float acc[4][4], int ty, int tx) {
#pragma unroll
  for (int kk = 0; kk < 16; ++kk) {
    const float4 av = *(const float4*)(&As[kk][ty << 2]);
    const float4 bv = *(const float4*)(&Bs[kk][tx << 2]);
    const float ar[4] = {av.x, av.y, av.z, av.w};
    const float br[4] = {bv.x, bv.y, bv.z, bv.w};
#pragma unroll
    for (int i = 0; i < 4; ++i)
#pragma unroll
      for (int j = 0; j < 4; ++j) acc[i][j] += ar[i] * br[j];
  }
}

__device__ __forceinline__ void store_tile(float* __restrict__ C, int ldc, int m0, int n0,
                                           const float acc[4][4], int ty, int tx) {
#pragma unroll
  for (int i = 0; i < 4; ++i) {
    const float4 v = make_float4(acc[i][0], acc[i][1], acc[i][2], acc[i][3]);
    *(float4*)(C + (size_t)(m0 + (ty << 2) + i) * ldc + n0 + (tx << 2)) = v;
  }
}

// ---------------- G[b] = B_b * B_b^T (+ row sums s) -------------------------------
// grid (4 tj, 4 ti, batch*8+kchunk), block (16,16). atomicAdd over 8 K-chunks of 512.
__global__ __launch_bounds__(256) void gram_kernel(const float* __restrict__ bin,
                                                   float* __restrict__ G,
                                                   float* __restrict__ srow) {
  const int tj = blockIdx.x, ti = blockIdx.y;
  const int batch = blockIdx.z >> 3, kc = blockIdx.z & 7;
  const float* bb = bin + (size_t)batch * CCH * NSP;
  __shared__ float As[16][68], Bs[16][68];
  const int tx = threadIdx.x, ty = threadIdx.y;
  const int tid = (ty << 4) | tx;
  const int r = tid >> 2, kq = (tid & 3) << 2;
  float acc[4][4] = {};
  float ssum = 0.f;
  for (int kt = 0; kt < 32; ++kt) {
    const int k0 = kc * 512 + kt * 16;
    const float4 av = *(const float4*)(bb + (size_t)(ti * 64 + r) * NSP + k0 + kq);
    const float4 bv = *(const float4*)(bb + (size_t)(tj * 64 + r) * NSP + k0 + kq);
    __syncthreads();
    As[kq + 0][r] = av.x; As[kq + 1][r] = av.y; As[kq + 2][r] = av.z; As[kq + 3][r] = av.w;
    Bs[kq + 0][r] = bv.x; Bs[kq + 1][r] = bv.y; Bs[kq + 2][r] = bv.z; Bs[kq + 3][r] = bv.w;
    __syncthreads();
    ssum += av.x + av.y + av.z + av.w;
    mm16(As, Bs, acc, ty, tx);
  }
  float* Gb = G + (size_t)batch * 65536;
#pragma unroll
  for (int i = 0; i < 4; ++i)
#pragma unroll
    for (int j = 0; j < 4; ++j)
      atomicAdd(&Gb[(size_t)(ti * 64 + (ty << 2) + i) * 256 + tj * 64 + (tx << 2) + j],
                acc[i][j]);
  if (ti == tj) atomicAdd(&srow[batch * 256 + ti * 64 + r], ssum);
}

// ---------------- batch-independent: Wg = W_w @ g_w ; PT = phi_w^T @ theta_w -------
__global__ __launch_bounds__(256) void prep_kernel(const float* __restrict__ W_w,
                                                   const float* __restrict__ g_w,
                                                   const float* __restrict__ phi_w,
                                                   const float* __restrict__ theta_w,
                                                   float* __restrict__ Wg,
                                                   float* __restrict__ PT) {
  __shared__ float As[16][68], Bs[16][68];
  const int n0 = blockIdx.x * 64, m0 = blockIdx.y * 64;
  const int tx = threadIdx.x, ty = threadIdx.y;
  const int tid = (ty << 4) | tx;
  float acc[4][4] = {};
  if (blockIdx.z == 0) {
    for (int kt = 0; kt < 8; ++kt) {   // K = 128
      __syncthreads();
      load_tr(W_w, CIN, m0, kt * 16, As, tid);
      load_dir(g_w, CCH, kt * 16, n0, Bs, tid);
      __syncthreads();
      mm16(As, Bs, acc, ty, tx);
    }
    store_tile(Wg, 256, m0, n0, acc, ty, tx);
  } else {
    for (int kt = 0; kt < 8; ++kt) {   // PT[m][n] = sum_k phi_w[k][m] theta_w[k][n]
      __syncthreads();
      load_dir(phi_w, CCH, kt * 16, m0, As, tid);
      load_dir(theta_w, CCH, kt * 16, n0, Bs, tid);
      __syncthreads();
      mm16(As, Bs, acc, ty, tx);
    }
    store_tile(PT, 256, m0, n0, acc, ty, tx);
  }
}

// ---------------- per-batch small vectors + bias chain + BN fold -------------------
// one block per batch, 256 threads
__global__ __launch_bounds__(256) void aux_kernel(
    const float* __restrict__ G, const float* __restrict__ srow,
    const float* __restrict__ Wg, const float* __restrict__ PT,
    const float* __restrict__ W_w, const float* __restrict__ theta_w,
    const float* __restrict__ phi_w, const float* __restrict__ g_w,
    const float* __restrict__ theta_b, const float* __restrict__ phi_b,
    const float* __restrict__ g_b,
    const float* __restrict__ bn_gamma, const float* __restrict__ bn_beta,
    const float* __restrict__ bn_mean, const float* __restrict__ bn_var,
    float* __restrict__ Wgs, float* __restrict__ sPT, float* __restrict__ wgb,
    float* __restrict__ vpt, float* __restrict__ bias_out) {
  const int b = blockIdx.x;
  const int t = threadIdx.x;
  __shared__ float ls[256], lvb[256], lt2[256];
  __shared__ float gb_s[128], pb_s[128], tb_s[128];
  __shared__ float t3_s[128], sp_s[128], sg_s[128], mtb_s[128];
  __shared__ float sd1, sd2;

  const float* Gb = G + (size_t)b * 65536;
  ls[t] = srow[b * 256 + t];
  if (t < 128) { gb_s[t] = g_b[t]; pb_s[t] = phi_b[t]; tb_s[t] = theta_b[t]; }
  __syncthreads();

  { // Wgs[o] = (Wg @ s)[o]
    float acc = 0.f;
    const float* row = Wg + (size_t)t * 256;
    for (int c = 0; c < 256; ++c) acc += row[c] * ls[c];
    Wgs[b * 256 + t] = acc;
  }
  { // sPT[c] = (s^T @ PT)[c]
    float acc = 0.f;
    for (int r2 = 0; r2 < 256; ++r2) acc += ls[r2] * PT[(size_t)r2 * 256 + t];
    sPT[b * 256 + t] = acc;
  }
  { // wgb = W_w @ g_b  (batch-indep; all blocks write identical values)
    float acc = 0.f;
    const float* row = W_w + (size_t)t * 128;
    for (int i = 0; i < 128; ++i) acc += row[i] * gb_s[i];
    wgb[t] = acc;
  }
  { // vpt[c] = (phi_b^T @ theta_w)[c]
    float acc = 0.f;
    for (int i = 0; i < 128; ++i) acc += pb_s[i] * theta_w[(size_t)i * 256 + t];
    vpt[t] = acc;
  }
  { // vb[c] = (phi_w^T @ theta_b)[c]
    float acc = 0.f;
    for (int i = 0; i < 128; ++i) acc += phi_w[(size_t)i * 256 + t] * tb_s[i];
    lvb[t] = acc;
  }
  __syncthreads();
  { // t2 = G @ vb
    float acc = 0.f;
    const float* row = Gb + (size_t)t * 256;
    for (int c = 0; c < 256; ++c) acc += row[c] * lvb[c];
    lt2[t] = acc;
  }
  __syncthreads();
  if (t < 128) {
    float t3 = 0.f, sp = 0.f, sg = 0.f;
    const float* gr = g_w + (size_t)t * 256;
    const float* pr = phi_w + (size_t)t * 256;
    for (int c = 0; c < 256; ++c) {
      t3 += gr[c] * lt2[c];   // g_w @ (G vb)
      sp += pr[c] * ls[c];    // phi_w @ s
      sg += gr[c] * ls[c];    // g_w @ s
    }
    t3_s[t] = t3; sp_s[t] = sp; sg_s[t] = sg;
  }
  __syncthreads();
  if (t == 0) {
    float d1 = 0.f, d2 = 0.f;
    for (int i = 0; i < 128; ++i) { d1 += pb_s[i] * tb_s[i]; d2 += sp_s[i] * tb_s[i]; }
    sd1 = d1; sd2 = d2;
  }
  __syncthreads();
  if (t < 128) mtb_s[t] = t3_s[t] + sg_s[t] * sd1 + gb_s[t] * (sd2 + 4096.0f * sd1);
  __syncthreads();
  { // bias_full = W_w @ mtb / N ; fold BN
    float acc = 0.f;
    const float* row = W_w + (size_t)t * 128;
    for (int i = 0; i < 128; ++i) acc += row[i] * mtb_s[i];
    const float bias_full = acc * (1.0f / 4096.0f);
    const float sc = bn_gamma[t] * rsqrtf(bn_var[t] + BN_EPS);
    bias_out[b * 256 + t] = sc * (bias_full - bn_mean[t]) + bn_beta[t];
  }
}

// ---------------- T1[b] = Wg @ G[b]  (grid 4,4,batch) ------------------------------
__global__ __launch_bounds__(256) void chainA_kernel(const float* __restrict__ Wg,
                                                     const float* __restrict__ G,
                                                     float* __restrict__ T1) {
  const int b = blockIdx.z;
  __shared__ float As[16][68], Bs[16][68];
  const int n0 = blockIdx.x * 64, m0 = blockIdx.y * 64;
  const int tx = threadIdx.x, ty = threadIdx.y;
  const int tid = (ty << 4) | tx;
  float acc[4][4] = {};
  for (int kt = 0; kt < 16; ++kt) {   // K = 256
    __syncthreads();
    load_tr(Wg, 256, m0, kt * 16, As, tid);
    load_dir(G + (size_t)b * 65536, 256, kt * 16, n0, Bs, tid);
    __syncthreads();
    mm16(As, Bs, acc, ty, tx);
  }
  store_tile(T1 + (size_t)b * 65536, 256, m0, n0, acc, ty, tx);
}

// ---------------- W_out[b] = scale * ((T1@PT + rank1)/N + rank1') -----------------
__global__ __launch_bounds__(256) void chainB_kernel(
    const float* __restrict__ T1, const float* __restrict__ PT,
    const float* __restrict__ Wgs, const float* __restrict__ sPT,
    const float* __restrict__ wgb, const float* __restrict__ vpt,
    const float* __restrict__ bn_gamma, const float* __restrict__ bn_var,
    float* __restrict__ W_out) {
  const int b = blockIdx.z;
  __shared__ float As[16][68], Bs[16][68];
  const int n0 = blockIdx.x * 64, m0 = blockIdx.y * 64;
  const int tx = threadIdx.x, ty = threadIdx.y;
  const int tid = (ty << 4) | tx;
  float acc[4][4] = {};
  for (int kt = 0; kt < 16; ++kt) {   // K = 256
    __syncthreads();
    load_tr(T1 + (size_t)b * 65536, 256, m0, kt * 16, As, tid);
    load_dir(PT, 256, kt * 16, n0, Bs, tid);
    __syncthreads();
    mm16(As, Bs, acc, ty, tx);
  }
  const float invN = 1.0f / 4096.0f;
#pragma unroll
  for (int i = 0; i < 4; ++i) {
    const int o = m0 + (ty << 2) + i;
    const float sc = bn_gamma[o] * rsqrtf(bn_var[o] + BN_EPS);
    const float wgs_o = Wgs[b * 256 + o];
    const float wgb_o = wgb[o];
    float tmp[4];
#pragma unroll
    for (int j = 0; j < 4; ++j) {
      const int c = n0 + (tx << 2) + j;
      tmp[j] = sc * ((acc[i][j] + wgs_o * vpt[c] + wgb_o * sPT[b * 256 + c]) * invN +
                     wgb_o * vpt[c]);
    }
    *(float4*)(W_out + (size_t)b * 65536 + (size_t)o * 256 + n0 + (tx << 2)) =
        make_float4(tmp[0], tmp[1], tmp[2], tmp[3]);
  }
}

// ---------------- out[b] = W_out[b] @ a[b] + bias_out[b] ---------------------------
// grid (64 n-tiles, 4 o-tiles, 4 batches)
__global__ __launch_bounds__(256) void out_kernel(const float* __restrict__ W_out,
                                                  const float* __restrict__ a,
                                                  const float* __restrict__ bias_out,
                                                  float* __restrict__ out) {
  const int b = blockIdx.z;
  const int n0 = blockIdx.x * 64, m0 = blockIdx.y * 64;
  __shared__ float As[16][68], Bs[16][68];
  const int tx = threadIdx.x, ty = threadIdx.y;
  const int tid = (ty << 4) | tx;
  float acc[4][4] = {};
  const float* Am = W_out + (size_t)b * 65536;
  const float* Bm = a + (size_t)b * CCH * NSP;
  for (int kt = 0; kt < 16; ++kt) {   // K = 256
    __syncthreads();
    load_tr(Am, 256, m0, kt * 16, As, tid);
    load_dir(Bm, NSP, kt * 16, n0, Bs, tid);
    __syncthreads();
    mm16(As, Bs, acc, ty, tx);
  }
#pragma unroll
  for (int i = 0; i < 4; ++i) {
    const int o = m0 + (ty << 2) + i;
    const float bo = bias_out[b * 256 + o];
    const float4 v = make_float4(acc[i][0] + bo, acc[i][1] + bo,
                                 acc[i][2] + bo, acc[i][3] + bo);
    *(float4*)(out + ((size_t)(b * 256 + o)) * NSP + n0 + (tx << 2)) = v;
  }
}

extern "C" void kernel_launch(void* const* d_in, const int* in_sizes, int n_in,
                              void* d_out, int out_size, void* d_ws, size_t ws_size,
                              hipStream_t stream) {
  (void)in_sizes; (void)n_in; (void)out_size; (void)ws_size;
  const float* a       = (const float*)d_in[0];
  const float* bI      = (const float*)d_in[1];
  const float* theta_w = (const float*)d_in[2];
  const float* theta_b = (const float*)d_in[3];
  const float* phi_w   = (const float*)d_in[4];
  const float* phi_b   = (const float*)d_in[5];
  const float* g_w     = (const float*)d_in[6];
  const float* g_b     = (const float*)d_in[7];
  const float* W_w     = (const float*)d_in[8];
  const float* bn_gamma= (const float*)d_in[9];
  const float* bn_beta = (const float*)d_in[10];
  const float* bn_mean = (const float*)d_in[11];
  const float* bn_var  = (const float*)d_in[12];
  float* out = (float*)d_out;
  float* ws  = (float*)d_ws;

  // workspace layout (floats), total ~922K floats = 3.7 MB
  float* G        = ws;            // 4*256*256 = 262144
  float* srow     = ws + 262144;   // 4*256     = 1024
  float* Wg       = ws + 263168;   // 65536
  float* PT       = ws + 328704;   // 65536
  float* T1       = ws + 394240;   // 262144
  float* W_out    = ws + 656384;   // 262144
  float* bias_out = ws + 918528;   // 1024
  float* Wgs      = ws + 919552;   // 1024
  float* sPTv     = ws + 920576;   // 1024
  float* wgb      = ws + 921600;   // 256
  float* vpt      = ws + 921856;   // 256

  hipMemsetAsync(G, 0, (262144 + 1024) * sizeof(float), stream);  // G + srow (atomics)

  gram_kernel<<<dim3(4, 4, 32), dim3(16, 16), 0, stream>>>(bI, G, srow);
  prep_kernel<<<dim3(4, 4, 2), dim3(16, 16), 0, stream>>>(W_w, g_w, phi_w, theta_w, Wg, PT);
  aux_kernel<<<dim3(4), dim3(256), 0, stream>>>(G, srow, Wg, PT, W_w, theta_w, phi_w, g_w,
                                                theta_b, phi_b, g_b,
                                                bn_gamma, bn_beta, bn_mean, bn_var,
                                                Wgs, sPTv, wgb, vpt, bias_out);
  chainA_kernel<<<dim3(4, 4, 4), dim3(16, 16), 0, stream>>>(Wg, G, T1);
  chainB_kernel<<<dim3(4, 4, 4), dim3(16, 16), 0, stream>>>(T1, PT, Wgs, sPTv, wgb, vpt,
                                                            bn_gamma, bn_var, W_out);
  out_kernel<<<dim3(64, 4, 4), dim3(16, 16), 0, stream>>>(W_out, a, bias_out, out);
}

// Round 2
// 260.340 us; speedup vs baseline: 1.0863x; 1.0863x over previous
//
#include <hip/hip_runtime.h>
#include <hip/hip_bf16.h>

#define NSP 4096   // H*W
#define CCH 256    // C
#define CIN 128    // Ci
#define BN_EPS 1e-5f

typedef __bf16 bf16x8 __attribute__((ext_vector_type(8)));
typedef __bf16 bf16x4 __attribute__((ext_vector_type(4)));
typedef float f32x4 __attribute__((ext_vector_type(4)));

// ================= fp32 tile helpers (used by prep/chainA/chainB) ================

__device__ __forceinline__ void load_tr(const float* __restrict__ A, int lda, int m0, int k0,
                                        float (*As)[68], int tid) {
  const int r = tid >> 2;
  const int kq = (tid & 3) << 2;
  const float4 v = *(const float4*)(A + (size_t)(m0 + r) * lda + k0 + kq);
  As[kq + 0][r] = v.x;
  As[kq + 1][r] = v.y;
  As[kq + 2][r] = v.z;
  As[kq + 3][r] = v.w;
}

__device__ __forceinline__ void load_dir(const float* __restrict__ B, int ldb, int k0, int n0,
                                         float (*Bs)[68], int tid) {
  const int kr = tid >> 4;
  const int nq = (tid & 15) << 2;
  const float4 v = *(const float4*)(B + (size_t)(k0 + kr) * ldb + n0 + nq);
  *(float4*)(&Bs[kr][nq]) = v;
}

__device__ __forceinline__ void mm16(const float (*As)[68], const float (*Bs)[68],
                                     float acc[4][4], int ty, int tx) {
#pragma unroll
  for (int kk = 0; kk < 16; ++kk) {
    const float4 av = *(const float4*)(&As[kk][ty << 2]);
    const float4 bv = *(const float4*)(&Bs[kk][tx << 2]);
    const float ar[4] = {av.x, av.y, av.z, av.w};
    const float br[4] = {bv.x, bv.y, bv.z, bv.w};
#pragma unroll
    for (int i = 0; i < 4; ++i)
#pragma unroll
      for (int j = 0; j < 4; ++j) acc[i][j] += ar[i] * br[j];
  }
}

__device__ __forceinline__ void store_tile(float* __restrict__ C, int ldc, int m0, int n0,
                                           const float acc[4][4], int ty, int tx) {
#pragma unroll
  for (int i = 0; i < 4; ++i) {
    const float4 v = make_float4(acc[i][0], acc[i][1], acc[i][2], acc[i][3]);
    *(float4*)(C + (size_t)(m0 + (ty << 2) + i) * ldc + n0 + (tx << 2)) = v;
  }
}

// ================= cast b -> bf16 hi/lo + exact fp32 row sums ====================
// one block per row of b (4*256 rows x 4096)
__global__ __launch_bounds__(256) void cast_b_kernel(const float* __restrict__ bin,
                                                     __bf16* __restrict__ bhi,
                                                     __bf16* __restrict__ blo,
                                                     float* __restrict__ srow) {
  const int row = blockIdx.x;
  const int t = threadIdx.x;
  const float* src = bin + (size_t)row * NSP + t * 16;
  float sum = 0.f;
  __bf16 hi[16], lo[16];
#pragma unroll
  for (int i = 0; i < 4; ++i) {
    const float4 v = *(const float4*)(src + i * 4);
    const float vv[4] = {v.x, v.y, v.z, v.w};
#pragma unroll
    for (int j = 0; j < 4; ++j) {
      const float x = vv[j];
      sum += x;
      const __bf16 h = (__bf16)x;
      hi[i * 4 + j] = h;
      lo[i * 4 + j] = (__bf16)(x - (float)h);
    }
  }
  __bf16* dh = bhi + (size_t)row * NSP + t * 16;
  __bf16* dl = blo + (size_t)row * NSP + t * 16;
  *(bf16x8*)dh = *(bf16x8*)&hi[0];
  *(bf16x8*)(dh + 8) = *(bf16x8*)&hi[8];
  *(bf16x8*)dl = *(bf16x8*)&lo[0];
  *(bf16x8*)(dl + 8) = *(bf16x8*)&lo[8];

  __shared__ float red[4];
#pragma unroll
  for (int off = 32; off; off >>= 1) sum += __shfl_down(sum, off);
  if ((t & 63) == 0) red[t >> 6] = sum;
  __syncthreads();
  if (t == 0) srow[row] = red[0] + red[1] + red[2] + red[3];
}

// ================= cast a -> bf16 transposed: at[b][n][c] ========================
// grid (64 n-tiles, 4 c-tiles, 4 batch), block 256
__global__ __launch_bounds__(256) void cast_a_kernel(const float* __restrict__ a,
                                                     __bf16* __restrict__ at) {
  const int n0 = blockIdx.x * 64, c0 = blockIdx.y * 64, b = blockIdx.z;
  __shared__ float tile[64][68];
  const int t = threadIdx.x;
  const int cr = t >> 4, nq = (t & 15) << 2;
  const float* src = a + ((size_t)(b * CCH + c0)) * NSP + n0;
#pragma unroll
  for (int s = 0; s < 4; ++s) {
    const float4 v = *(const float4*)(src + (size_t)(cr + s * 16) * NSP + nq);
    *(float4*)&tile[cr + s * 16][nq] = v;
  }
  __syncthreads();
  const int n = t >> 2, cq = (t & 3) << 4;
  __bf16 outv[16];
#pragma unroll
  for (int i = 0; i < 16; ++i) outv[i] = (__bf16)tile[cq + i][n];
  __bf16* dst = at + ((size_t)(b * NSP + n0 + n)) * CCH + c0 + cq;
  *(bf16x8*)dst = *(bf16x8*)&outv[0];
  *(bf16x8*)(dst + 8) = *(bf16x8*)&outv[8];
}

// ================= G[b] = B_b B_b^T via MFMA bf16 hi/lo ==========================
// grid (4 jt, 4 it, batch*8 + kc), block 256 (4 waves). K chunks of 512, atomicAdd.
__global__ __launch_bounds__(256) void gram_mfma_kernel(const __bf16* __restrict__ bhi,
                                                        const __bf16* __restrict__ blo,
                                                        float* __restrict__ G) {
  const int jt = blockIdx.x, it = blockIdx.y;
  const int batch = blockIdx.z >> 3, kc = blockIdx.z & 7;
  const int wave = threadIdx.x >> 6, lane = threadIdx.x & 63;
  const int m = lane & 15, q = lane >> 4;
  const size_t base = (size_t)batch * CCH * NSP;
  const size_t arow = base + (size_t)(it * 64 + wave * 16 + m) * NSP;
  f32x4 acc[4] = {};
  for (int ks = 0; ks < 16; ++ks) {
    const int k = kc * 512 + ks * 32 + q * 8;
    const bf16x8 ah = *(const bf16x8*)(bhi + arow + k);
    const bf16x8 al = *(const bf16x8*)(blo + arow + k);
#pragma unroll
    for (int t4 = 0; t4 < 4; ++t4) {
      const size_t brow = base + (size_t)(jt * 64 + t4 * 16 + m) * NSP;
      const bf16x8 bh = *(const bf16x8*)(bhi + brow + k);
      const bf16x8 bl = *(const bf16x8*)(blo + brow + k);
      acc[t4] = __builtin_amdgcn_mfma_f32_16x16x32_bf16(ah, bh, acc[t4], 0, 0, 0);
      acc[t4] = __builtin_amdgcn_mfma_f32_16x16x32_bf16(ah, bl, acc[t4], 0, 0, 0);
      acc[t4] = __builtin_amdgcn_mfma_f32_16x16x32_bf16(al, bh, acc[t4], 0, 0, 0);
    }
  }
  float* Gb = G + (size_t)batch * 65536;
#pragma unroll
  for (int t4 = 0; t4 < 4; ++t4)
#pragma unroll
    for (int r = 0; r < 4; ++r)
      atomicAdd(&Gb[(size_t)(it * 64 + wave * 16 + q * 4 + r) * 256 +
                    jt * 64 + t4 * 16 + m],
                acc[t4][r]);
}

// ================= batch-independent: Wg = W_w @ g_w ; PT = phi_w^T @ theta_w ====
__global__ __launch_bounds__(256) void prep_kernel(const float* __restrict__ W_w,
                                                   const float* __restrict__ g_w,
                                                   const float* __restrict__ phi_w,
                                                   const float* __restrict__ theta_w,
                                                   float* __restrict__ Wg,
                                                   float* __restrict__ PT) {
  __shared__ float As[16][68], Bs[16][68];
  const int n0 = blockIdx.x * 64, m0 = blockIdx.y * 64;
  const int tx = threadIdx.x, ty = threadIdx.y;
  const int tid = (ty << 4) | tx;
  float acc[4][4] = {};
  if (blockIdx.z == 0) {
    for (int kt = 0; kt < 8; ++kt) {
      __syncthreads();
      load_tr(W_w, CIN, m0, kt * 16, As, tid);
      load_dir(g_w, CCH, kt * 16, n0, Bs, tid);
      __syncthreads();
      mm16(As, Bs, acc, ty, tx);
    }
    store_tile(Wg, 256, m0, n0, acc, ty, tx);
  } else {
    for (int kt = 0; kt < 8; ++kt) {
      __syncthreads();
      load_dir(phi_w, CCH, kt * 16, m0, As, tid);
      load_dir(theta_w, CCH, kt * 16, n0, Bs, tid);
      __syncthreads();
      mm16(As, Bs, acc, ty, tx);
    }
    store_tile(PT, 256, m0, n0, acc, ty, tx);
  }
}

// ================= per-batch small vectors + bias chain + BN fold ================
__global__ __launch_bounds__(256) void aux_kernel(
    const float* __restrict__ G, const float* __restrict__ srow,
    const float* __restrict__ Wg, const float* __restrict__ PT,
    const float* __restrict__ W_w, const float* __restrict__ theta_w,
    const float* __restrict__ phi_w, const float* __restrict__ g_w,
    const float* __restrict__ theta_b, const float* __restrict__ phi_b,
    const float* __restrict__ g_b,
    const float* __restrict__ bn_gamma, const float* __restrict__ bn_beta,
    const float* __restrict__ bn_mean, const float* __restrict__ bn_var,
    float* __restrict__ Wgs, float* __restrict__ sPT, float* __restrict__ wgb,
    float* __restrict__ vpt, float* __restrict__ bias_out) {
  const int b = blockIdx.x;
  const int t = threadIdx.x;
  __shared__ float ls[256], lvb[256], lt2[256];
  __shared__ float gb_s[128], pb_s[128], tb_s[128];
  __shared__ float t3_s[128], sp_s[128], sg_s[128], mtb_s[128];
  __shared__ float sd1, sd2;

  const float* Gb = G + (size_t)b * 65536;
  ls[t] = srow[b * 256 + t];
  if (t < 128) { gb_s[t] = g_b[t]; pb_s[t] = phi_b[t]; tb_s[t] = theta_b[t]; }
  __syncthreads();

  {
    float acc = 0.f;
    const float* row = Wg + (size_t)t * 256;
    for (int c = 0; c < 256; ++c) acc += row[c] * ls[c];
    Wgs[b * 256 + t] = acc;
  }
  {
    float acc = 0.f;
    for (int r2 = 0; r2 < 256; ++r2) acc += ls[r2] * PT[(size_t)r2 * 256 + t];
    sPT[b * 256 + t] = acc;
  }
  {
    float acc = 0.f;
    const float* row = W_w + (size_t)t * 128;
    for (int i = 0; i < 128; ++i) acc += row[i] * gb_s[i];
    wgb[t] = acc;
  }
  {
    float acc = 0.f;
    for (int i = 0; i < 128; ++i) acc += pb_s[i] * theta_w[(size_t)i * 256 + t];
    vpt[t] = acc;
  }
  {
    float acc = 0.f;
    for (int i = 0; i < 128; ++i) acc += phi_w[(size_t)i * 256 + t] * tb_s[i];
    lvb[t] = acc;
  }
  __syncthreads();
  {
    float acc = 0.f;
    const float* row = Gb + (size_t)t * 256;
    for (int c = 0; c < 256; ++c) acc += row[c] * lvb[c];
    lt2[t] = acc;
  }
  __syncthreads();
  if (t < 128) {
    float t3 = 0.f, sp = 0.f, sg = 0.f;
    const float* gr = g_w + (size_t)t * 256;
    const float* pr = phi_w + (size_t)t * 256;
    for (int c = 0; c < 256; ++c) {
      t3 += gr[c] * lt2[c];
      sp += pr[c] * ls[c];
      sg += gr[c] * ls[c];
    }
    t3_s[t] = t3; sp_s[t] = sp; sg_s[t] = sg;
  }
  __syncthreads();
  if (t == 0) {
    float d1 = 0.f, d2 = 0.f;
    for (int i = 0; i < 128; ++i) { d1 += pb_s[i] * tb_s[i]; d2 += sp_s[i] * tb_s[i]; }
    sd1 = d1; sd2 = d2;
  }
  __syncthreads();
  if (t < 128) mtb_s[t] = t3_s[t] + sg_s[t] * sd1 + gb_s[t] * (sd2 + 4096.0f * sd1);
  __syncthreads();
  {
    float acc = 0.f;
    const float* row = W_w + (size_t)t * 128;
    for (int i = 0; i < 128; ++i) acc += row[i] * mtb_s[i];
    const float bias_full = acc * (1.0f / 4096.0f);
    const float sc = bn_gamma[t] * rsqrtf(bn_var[t] + BN_EPS);
    bias_out[b * 256 + t] = sc * (bias_full - bn_mean[t]) + bn_beta[t];
  }
}

// ================= T1[b] = Wg @ G[b] =============================================
__global__ __launch_bounds__(256) void chainA_kernel(const float* __restrict__ Wg,
                                                     const float* __restrict__ G,
                                                     float* __restrict__ T1) {
  const int b = blockIdx.z;
  __shared__ float As[16][68], Bs[16][68];
  const int n0 = blockIdx.x * 64, m0 = blockIdx.y * 64;
  const int tx = threadIdx.x, ty = threadIdx.y;
  const int tid = (ty << 4) | tx;
  float acc[4][4] = {};
  for (int kt = 0; kt < 16; ++kt) {
    __syncthreads();
    load_tr(Wg, 256, m0, kt * 16, As, tid);
    load_dir(G + (size_t)b * 65536, 256, kt * 16, n0, Bs, tid);
    __syncthreads();
    mm16(As, Bs, acc, ty, tx);
  }
  store_tile(T1 + (size_t)b * 65536, 256, m0, n0, acc, ty, tx);
}

// ================= W_out[b] (bf16 hi/lo) = scale*((T1@PT + rank1)/N + rank1') ====
__global__ __launch_bounds__(256) void chainB_kernel(
    const float* __restrict__ T1, const float* __restrict__ PT,
    const float* __restrict__ Wgs, const float* __restrict__ sPT,
    const float* __restrict__ wgb, const float* __restrict__ vpt,
    const float* __restrict__ bn_gamma, const float* __restrict__ bn_var,
    __bf16* __restrict__ Whi, __bf16* __restrict__ Wlo) {
  const int b = blockIdx.z;
  __shared__ float As[16][68], Bs[16][68];
  const int n0 = blockIdx.x * 64, m0 = blockIdx.y * 64;
  const int tx = threadIdx.x, ty = threadIdx.y;
  const int tid = (ty << 4) | tx;
  float acc[4][4] = {};
  for (int kt = 0; kt < 16; ++kt) {
    __syncthreads();
    load_tr(T1 + (size_t)b * 65536, 256, m0, kt * 16, As, tid);
    load_dir(PT, 256, kt * 16, n0, Bs, tid);
    __syncthreads();
    mm16(As, Bs, acc, ty, tx);
  }
  const float invN = 1.0f / 4096.0f;
#pragma unroll
  for (int i = 0; i < 4; ++i) {
    const int o = m0 + (ty << 2) + i;
    const float sc = bn_gamma[o] * rsqrtf(bn_var[o] + BN_EPS);
    const float wgs_o = Wgs[b * 256 + o];
    const float wgb_o = wgb[o];
    __bf16 h4[4], l4[4];
#pragma unroll
    for (int j = 0; j < 4; ++j) {
      const int c = n0 + (tx << 2) + j;
      const float w = sc * ((acc[i][j] + wgs_o * vpt[c] + wgb_o * sPT[b * 256 + c]) * invN +
                            wgb_o * vpt[c]);
      const __bf16 h = (__bf16)w;
      h4[j] = h;
      l4[j] = (__bf16)(w - (float)h);
    }
    __bf16* dh = Whi + (size_t)b * 65536 + (size_t)o * 256 + n0 + (tx << 2);
    __bf16* dl = Wlo + (size_t)b * 65536 + (size_t)o * 256 + n0 + (tx << 2);
    *(bf16x4*)dh = *(bf16x4*)h4;
    *(bf16x4*)dl = *(bf16x4*)l4;
  }
}

// ================= out[b] = W_out[b] @ a[b] + bias  (MFMA) =======================
// grid (64 n-tiles, 4 o-tiles, 4 batch), block 256 (4 waves), K=256
__global__ __launch_bounds__(256) void out_mfma_kernel(const __bf16* __restrict__ Whi,
                                                       const __bf16* __restrict__ Wlo,
                                                       const __bf16* __restrict__ at,
                                                       const float* __restrict__ bias_out,
                                                       float* __restrict__ out) {
  const int nt = blockIdx.x, mt = blockIdx.y, b = blockIdx.z;
  const int wave = threadIdx.x >> 6, lane = threadIdx.x & 63;
  const int m = lane & 15, q = lane >> 4;
  const int o = mt * 64 + wave * 16 + m;
  const __bf16* wh = Whi + (size_t)b * 65536 + (size_t)o * 256;
  const __bf16* wl = Wlo + (size_t)b * 65536 + (size_t)o * 256;
  const __bf16* atb = at + (size_t)b * NSP * CCH;
  f32x4 acc[4] = {};
#pragma unroll
  for (int ks = 0; ks < 8; ++ks) {
    const int k = ks * 32 + q * 8;
    const bf16x8 ah = *(const bf16x8*)(wh + k);
    const bf16x8 al = *(const bf16x8*)(wl + k);
#pragma unroll
    for (int t4 = 0; t4 < 4; ++t4) {
      const bf16x8 bh = *(const bf16x8*)(atb + (size_t)(nt * 64 + t4 * 16 + m) * 256 + k);
      acc[t4] = __builtin_amdgcn_mfma_f32_16x16x32_bf16(ah, bh, acc[t4], 0, 0, 0);
      acc[t4] = __builtin_amdgcn_mfma_f32_16x16x32_bf16(al, bh, acc[t4], 0, 0, 0);
    }
  }
  float* ob = out + (size_t)b * CCH * NSP;
#pragma unroll
  for (int r = 0; r < 4; ++r) {
    const int orow = mt * 64 + wave * 16 + q * 4 + r;
    const float bo = bias_out[b * 256 + orow];
#pragma unroll
    for (int t4 = 0; t4 < 4; ++t4)
      ob[(size_t)orow * NSP + nt * 64 + t4 * 16 + m] = acc[t4][r] + bo;
  }
}

extern "C" void kernel_launch(void* const* d_in, const int* in_sizes, int n_in,
                              void* d_out, int out_size, void* d_ws, size_t ws_size,
                              hipStream_t stream) {
  (void)in_sizes; (void)n_in; (void)out_size; (void)ws_size;
  const float* a       = (const float*)d_in[0];
  const float* bI      = (const float*)d_in[1];
  const float* theta_w = (const float*)d_in[2];
  const float* theta_b = (const float*)d_in[3];
  const float* phi_w   = (const float*)d_in[4];
  const float* phi_b   = (const float*)d_in[5];
  const float* g_w     = (const float*)d_in[6];
  const float* g_b     = (const float*)d_in[7];
  const float* W_w     = (const float*)d_in[8];
  const float* bn_gamma= (const float*)d_in[9];
  const float* bn_beta = (const float*)d_in[10];
  const float* bn_mean = (const float*)d_in[11];
  const float* bn_var  = (const float*)d_in[12];
  float* out = (float*)d_out;
  float* ws  = (float*)d_ws;

  // fp32 region (floats)
  float* G        = ws;                  // 262144
  float* srow     = ws + 262144;         // 1024
  float* Wg       = ws + 263168;         // 65536
  float* PT       = ws + 328704;         // 65536
  float* T1       = ws + 394240;         // 262144
  float* bias_out = ws + 656384;         // 1024
  float* Wgs      = ws + 657408;         // 1024
  float* sPTv     = ws + 658432;         // 1024
  float* wgb      = ws + 659456;         // 256
  float* vpt      = ws + 659712;         // 256   (end: 659968)
  // bf16 region (~18 MB total incl. fp32 part)
  __bf16* bhi = (__bf16*)(ws + 660480);      // 4*256*4096 bf16 = 8 MB
  __bf16* blo = (__bf16*)(ws + 2757632);     // 8 MB
  __bf16* Whi = (__bf16*)(ws + 4854784);     // 0.5 MB
  __bf16* Wlo = (__bf16*)(ws + 4985856);     // 0.5 MB (end float idx 5116928 = 20.5 MB)
  __bf16* at  = bhi;  // alias: bhi dead after gram; cast_a runs after gram (stream order)

  hipMemsetAsync(G, 0, 263168 * sizeof(float), stream);  // G + srow

  cast_b_kernel<<<dim3(1024), dim3(256), 0, stream>>>(bI, bhi, blo, srow);
  gram_mfma_kernel<<<dim3(4, 4, 32), dim3(256), 0, stream>>>(bhi, blo, G);
  cast_a_kernel<<<dim3(64, 4, 4), dim3(256), 0, stream>>>(a, at);
  prep_kernel<<<dim3(4, 4, 2), dim3(16, 16), 0, stream>>>(W_w, g_w, phi_w, theta_w, Wg, PT);
  aux_kernel<<<dim3(4), dim3(256), 0, stream>>>(G, srow, Wg, PT, W_w, theta_w, phi_w, g_w,
                                                theta_b, phi_b, g_b,
                                                bn_gamma, bn_beta, bn_mean, bn_var,
                                                Wgs, sPTv, wgb, vpt, bias_out);
  chainA_kernel<<<dim3(4, 4, 4), dim3(16, 16), 0, stream>>>(Wg, G, T1);
  chainB_kernel<<<dim3(4, 4, 4), dim3(16, 16), 0, stream>>>(T1, PT, Wgs, sPTv, wgb, vpt,
                                                            bn_gamma, bn_var, Whi, Wlo);
  out_mfma_kernel<<<dim3(64, 4, 4), dim3(256), 0, stream>>>(Whi, Wlo, at, bias_out, out);
}

// Round 3
// 246.898 us; speedup vs baseline: 1.1454x; 1.0544x over previous
//
#include <hip/hip_runtime.h>
#include <hip/hip_bf16.h>

#define NSP 4096   // H*W
#define CCH 256    // C
#define CIN 128    // Ci
#define BN_EPS 1e-5f

typedef __bf16 bf16x8 __attribute__((ext_vector_type(8)));
typedef __bf16 bf16x4 __attribute__((ext_vector_type(4)));
typedef float f32x4 __attribute__((ext_vector_type(4)));

// ================= fp32 tile helpers (prep/chainA/chainB) ========================

__device__ __forceinline__ float4 fetch_tr(const float* __restrict__ A, int lda, int m0,
                                           int k0, int tid) {
  const int r = tid >> 2, kq = (tid & 3) << 2;
  return *(const float4*)(A + (size_t)(m0 + r) * lda + k0 + kq);
}
__device__ __forceinline__ void stash_tr(float (*As)[68], float4 v, int tid) {
  const int r = tid >> 2, kq = (tid & 3) << 2;
  As[kq + 0][r] = v.x; As[kq + 1][r] = v.y; As[kq + 2][r] = v.z; As[kq + 3][r] = v.w;
}
__device__ __forceinline__ float4 fetch_dir(const float* __restrict__ B, int ldb, int k0,
                                            int n0, int tid) {
  const int kr = tid >> 4, nq = (tid & 15) << 2;
  return *(const float4*)(B + (size_t)(k0 + kr) * ldb + n0 + nq);
}
__device__ __forceinline__ void stash_dir(float (*Bs)[68], float4 v, int tid) {
  const int kr = tid >> 4, nq = (tid & 15) << 2;
  *(float4*)(&Bs[kr][nq]) = v;
}

__device__ __forceinline__ void mm16(const float (*As)[68], const float (*Bs)[68],
                                     float acc[4][4], int ty, int tx) {
#pragma unroll
  for (int kk = 0; kk < 16; ++kk) {
    const float4 av = *(const float4*)(&As[kk][ty << 2]);
    const float4 bv = *(const float4*)(&Bs[kk][tx << 2]);
    const float ar[4] = {av.x, av.y, av.z, av.w};
    const float br[4] = {bv.x, bv.y, bv.z, bv.w};
#pragma unroll
    for (int i = 0; i < 4; ++i)
#pragma unroll
      for (int j = 0; j < 4; ++j) acc[i][j] += ar[i] * br[j];
  }
}

__device__ __forceinline__ void store_tile(float* __restrict__ C, int ldc, int m0, int n0,
                                           const float acc[4][4], int ty, int tx) {
#pragma unroll
  for (int i = 0; i < 4; ++i) {
    const float4 v = make_float4(acc[i][0], acc[i][1], acc[i][2], acc[i][3]);
    *(float4*)(C + (size_t)(m0 + (ty << 2) + i) * ldc + n0 + (tx << 2)) = v;
  }
}

__device__ __forceinline__ float wave_reduce(float v) {
#pragma unroll
  for (int off = 32; off; off >>= 1) v += __shfl_down(v, off);
  return v;  // valid in lane 0
}

// ================= setup: cast_b (blocks 0..1023) + prep (1024..1055) ============
__global__ __launch_bounds__(256) void setup_kernel(
    const float* __restrict__ bin, __bf16* __restrict__ bhi, __bf16* __restrict__ blo,
    float* __restrict__ srow, const float* __restrict__ W_w, const float* __restrict__ g_w,
    const float* __restrict__ phi_w, const float* __restrict__ theta_w,
    float* __restrict__ Wg, float* __restrict__ PT) {
  __shared__ float smem[2 * 16 * 68];
  const int idx = blockIdx.x;
  const int t = threadIdx.x;
  if (idx < 1024) {
    // ---- cast b row -> bf16 hi/lo + exact fp32 row sum ----
    const int row = idx;
    const float* src = bin + (size_t)row * NSP + t * 16;
    float sum = 0.f;
    __bf16 hi[16], lo[16];
#pragma unroll
    for (int i = 0; i < 4; ++i) {
      const float4 v = *(const float4*)(src + i * 4);
      const float vv[4] = {v.x, v.y, v.z, v.w};
#pragma unroll
      for (int j = 0; j < 4; ++j) {
        const float x = vv[j];
        sum += x;
        const __bf16 h = (__bf16)x;
        hi[i * 4 + j] = h;
        lo[i * 4 + j] = (__bf16)(x - (float)h);
      }
    }
    __bf16* dh = bhi + (size_t)row * NSP + t * 16;
    __bf16* dl = blo + (size_t)row * NSP + t * 16;
    *(bf16x8*)dh = *(bf16x8*)&hi[0];
    *(bf16x8*)(dh + 8) = *(bf16x8*)&hi[8];
    *(bf16x8*)dl = *(bf16x8*)&lo[0];
    *(bf16x8*)(dl + 8) = *(bf16x8*)&lo[8];
#pragma unroll
    for (int off = 32; off; off >>= 1) sum += __shfl_down(sum, off);
    if ((t & 63) == 0) smem[t >> 6] = sum;
    __syncthreads();
    if (t == 0) srow[row] = smem[0] + smem[1] + smem[2] + smem[3];
  } else {
    // ---- prep: Wg = W_w @ g_w (z=0) ; PT = phi_w^T @ theta_w (z=1) ----
    const int p = idx - 1024;
    const int zsel = p >> 4, rem = p & 15;
    const int m0 = (rem >> 2) * 64, n0 = (rem & 3) * 64;
    float (*As)[68] = (float(*)[68])smem;
    float (*Bs)[68] = (float(*)[68])(smem + 16 * 68);
    const int ty = t >> 4, tx = t & 15;
    float acc[4][4] = {};
    if (zsel == 0) {
      float4 ar = fetch_tr(W_w, CIN, m0, 0, t);
      float4 br = fetch_dir(g_w, CCH, 0, n0, t);
      for (int kt = 0; kt < 8; ++kt) {
        stash_tr(As, ar, t); stash_dir(Bs, br, t);
        __syncthreads();
        if (kt < 7) { ar = fetch_tr(W_w, CIN, m0, (kt + 1) * 16, t);
                      br = fetch_dir(g_w, CCH, (kt + 1) * 16, n0, t); }
        mm16(As, Bs, acc, ty, tx);
        __syncthreads();
      }
      store_tile(Wg, 256, m0, n0, acc, ty, tx);
    } else {
      float4 ar = fetch_dir(phi_w, CCH, 0, m0, t);
      float4 br = fetch_dir(theta_w, CCH, 0, n0, t);
      for (int kt = 0; kt < 8; ++kt) {
        stash_dir(As, ar, t); stash_dir(Bs, br, t);
        __syncthreads();
        if (kt < 7) { ar = fetch_dir(phi_w, CCH, (kt + 1) * 16, m0, t);
                      br = fetch_dir(theta_w, CCH, (kt + 1) * 16, n0, t); }
        mm16(As, Bs, acc, ty, tx);
        __syncthreads();
      }
      store_tile(PT, 256, m0, n0, acc, ty, tx);
    }
  }
}

// ================= cast a -> bf16 transposed: at[b][n][c] ========================
__global__ __launch_bounds__(256) void cast_a_kernel(const float* __restrict__ a,
                                                     __bf16* __restrict__ at) {
  const int n0 = blockIdx.x * 64, c0 = blockIdx.y * 64, b = blockIdx.z;
  __shared__ float tile[64][68];
  const int t = threadIdx.x;
  const int cr = t >> 4, nq = (t & 15) << 2;
  const float* src = a + ((size_t)(b * CCH + c0)) * NSP + n0;
#pragma unroll
  for (int s = 0; s < 4; ++s) {
    const float4 v = *(const float4*)(src + (size_t)(cr + s * 16) * NSP + nq);
    *(float4*)&tile[cr + s * 16][nq] = v;
  }
  __syncthreads();
  const int n = t >> 2, cq = (t & 3) << 4;
  __bf16 outv[16];
#pragma unroll
  for (int i = 0; i < 16; ++i) outv[i] = (__bf16)tile[cq + i][n];
  __bf16* dst = at + ((size_t)(b * NSP + n0 + n)) * CCH + c0 + cq;
  *(bf16x8*)dst = *(bf16x8*)&outv[0];
  *(bf16x8*)(dst + 8) = *(bf16x8*)&outv[8];
}

// ================= G[b] = B_b B_b^T via MFMA bf16 hi/lo ==========================
__global__ __launch_bounds__(256) void gram_mfma_kernel(const __bf16* __restrict__ bhi,
                                                        const __bf16* __restrict__ blo,
                                                        float* __restrict__ G) {
  const int jt = blockIdx.x, it = blockIdx.y;
  const int batch = blockIdx.z >> 3, kc = blockIdx.z & 7;
  const int wave = threadIdx.x >> 6, lane = threadIdx.x & 63;
  const int m = lane & 15, q = lane >> 4;
  const size_t base = (size_t)batch * CCH * NSP;
  const size_t arow = base + (size_t)(it * 64 + wave * 16 + m) * NSP;
  f32x4 acc[4] = {};
  for (int ks = 0; ks < 16; ++ks) {
    const int k = kc * 512 + ks * 32 + q * 8;
    const bf16x8 ah = *(const bf16x8*)(bhi + arow + k);
    const bf16x8 al = *(const bf16x8*)(blo + arow + k);
#pragma unroll
    for (int t4 = 0; t4 < 4; ++t4) {
      const size_t brow = base + (size_t)(jt * 64 + t4 * 16 + m) * NSP;
      const bf16x8 bh = *(const bf16x8*)(bhi + brow + k);
      const bf16x8 bl = *(const bf16x8*)(blo + brow + k);
      acc[t4] = __builtin_amdgcn_mfma_f32_16x16x32_bf16(ah, bh, acc[t4], 0, 0, 0);
      acc[t4] = __builtin_amdgcn_mfma_f32_16x16x32_bf16(ah, bl, acc[t4], 0, 0, 0);
      acc[t4] = __builtin_amdgcn_mfma_f32_16x16x32_bf16(al, bh, acc[t4], 0, 0, 0);
    }
  }
  float* Gb = G + (size_t)batch * 65536;
#pragma unroll
  for (int t4 = 0; t4 < 4; ++t4)
#pragma unroll
    for (int r = 0; r < 4; ++r)
      atomicAdd(&Gb[(size_t)(it * 64 + wave * 16 + q * 4 + r) * 256 +
                    jt * 64 + t4 * 16 + m],
                acc[t4][r]);
}

// ================= auxA: all matvecs not needing G ===============================
// grid 5 x 1024 threads. Blocks 0..3: per-batch sp,sg -> Wgs,sPTv,d2.
// Block 4: batch-independent vpt, vb, wgb, d1.
__global__ __launch_bounds__(1024) void auxA_kernel(
    const float* __restrict__ srow, const float* __restrict__ W_w,
    const float* __restrict__ g_w, const float* __restrict__ phi_w,
    const float* __restrict__ theta_w, const float* __restrict__ theta_b,
    const float* __restrict__ phi_b, const float* __restrict__ g_b,
    float* __restrict__ Wgs, float* __restrict__ sPTv, float* __restrict__ wgb,
    float* __restrict__ vpt, float* __restrict__ vb_g, float* __restrict__ sg_g,
    float* __restrict__ dvec) {
  const int blk = blockIdx.x;
  const int t = threadIdx.x;
  const int wave = t >> 6, lane = t & 63;
  if (blk < 4) {
    const int b = blk;
    __shared__ float s_s[256], sp_s[128], sg_s[128];
    if (t < 256) s_s[t] = srow[b * 256 + t];
    __syncthreads();
    // phase 1: sp = phi_w@s (j<128), sg = g_w@s (j>=128): wave-dots len-256
    const float4 sv = *(const float4*)&s_s[lane * 4];
    for (int j = wave; j < 256; j += 16) {
      const float* row = (j < 128) ? (phi_w + (size_t)j * 256)
                                   : (g_w + (size_t)(j - 128) * 256);
      const float4 r = *(const float4*)(row + lane * 4);
      float v = r.x * sv.x + r.y * sv.y + r.z * sv.z + r.w * sv.w;
      v = wave_reduce(v);
      if (lane == 0) { if (j < 128) sp_s[j] = v; else sg_s[j - 128] = v; }
    }
    __syncthreads();
    if (t < 128) sg_g[b * 128 + t] = sg_s[t];
    // phase 2a (waves 0..3): sPTv[c] = sum_i sp[i]*theta_w[i][c]  (coalesced cols)
    if (t < 256) {
      float acc = 0.f;
#pragma unroll 8
      for (int i = 0; i < 128; ++i) acc += sp_s[i] * theta_w[(size_t)i * 256 + t];
      sPTv[b * 256 + t] = acc;
      // d2 = sp . theta_b (wave 0)
      if (wave == 0) {
        float pv = sp_s[lane] * theta_b[lane] + sp_s[lane + 64] * theta_b[lane + 64];
        pv = wave_reduce(pv);
        if (lane == 0) dvec[1 + b] = pv;
      }
    } else {
      // phase 2b (waves 4..15): Wgs[o] = W_w[o] . sg : wave-dots len-128
      const float2 mv = *(const float2*)&sg_s[lane * 2];
      for (int o = wave - 4; o < 256; o += 12) {
        const float2 r = *(const float2*)(W_w + (size_t)o * 128 + lane * 2);
        float v = r.x * mv.x + r.y * mv.y;
        v = wave_reduce(v);
        if (lane == 0) Wgs[b * 256 + o] = v;
      }
    }
  } else {
    __shared__ float pb_s[128], tb_s[128], gb_s[128];
    if (t < 128) { pb_s[t] = phi_b[t]; tb_s[t] = theta_b[t]; gb_s[t] = g_b[t]; }
    __syncthreads();
    if (t < 256) {
      // vpt[c] = sum_i phi_b[i]*theta_w[i][c]
      float acc = 0.f;
#pragma unroll 8
      for (int i = 0; i < 128; ++i) acc += pb_s[i] * theta_w[(size_t)i * 256 + t];
      vpt[t] = acc;
      if (wave == 0) {  // d1 = phi_b . theta_b
        float pv = pb_s[lane] * tb_s[lane] + pb_s[lane + 64] * tb_s[lane + 64];
        pv = wave_reduce(pv);
        if (lane == 0) dvec[0] = pv;
      }
    } else if (t < 512) {
      // vb[c] = sum_i phi_w[i][c]*theta_b[i]
      const int c = t - 256;
      float acc = 0.f;
#pragma unroll 8
      for (int i = 0; i < 128; ++i) acc += phi_w[(size_t)i * 256 + c] * tb_s[i];
      vb_g[c] = acc;
    } else {
      // wgb[o] = W_w[o] . g_b : wave-dots len-128 (waves 8..15)
      const float2 gv = *(const float2*)&gb_s[lane * 2];
      for (int o = wave - 8; o < 256; o += 8) {
        const float2 r = *(const float2*)(W_w + (size_t)o * 128 + lane * 2);
        float v = r.x * gv.x + r.y * gv.y;
        v = wave_reduce(v);
        if (lane == 0) wgb[o] = v;
      }
    }
  }
}

// ================= auxB: dependent chain t2 -> t3 -> mtb -> bias ================
// grid 4 x 1024 threads (one block per batch)
__global__ __launch_bounds__(1024) void auxB_kernel(
    const float* __restrict__ G, const float* __restrict__ vb_g,
    const float* __restrict__ sg_g, const float* __restrict__ dvec,
    const float* __restrict__ g_w, const float* __restrict__ g_b,
    const float* __restrict__ W_w,
    const float* __restrict__ bn_gamma, const float* __restrict__ bn_beta,
    const float* __restrict__ bn_mean, const float* __restrict__ bn_var,
    float* __restrict__ bias_out) {
  const int b = blockIdx.x;
  const int t = threadIdx.x;
  const int wave = t >> 6, lane = t & 63;
  __shared__ float vb_s[256], t2_s[256], mtb_s[128], sgb_s[128], gbb_s[128];
  if (t < 256) vb_s[t] = vb_g[t];
  if (t >= 256 && t < 384) sgb_s[t - 256] = sg_g[b * 128 + (t - 256)];
  if (t >= 384 && t < 512) gbb_s[t - 384] = g_b[t - 384];
  __syncthreads();
  const float d1 = dvec[0], d2 = dvec[1 + b];
  const float* Gb = G + (size_t)b * 65536;
  // t2 = G @ vb : wave-dots len-256
  {
    const float4 vv = *(const float4*)&vb_s[lane * 4];
    for (int o = wave; o < 256; o += 16) {
      const float4 r = *(const float4*)(Gb + (size_t)o * 256 + lane * 4);
      float v = r.x * vv.x + r.y * vv.y + r.z * vv.z + r.w * vv.w;
      v = wave_reduce(v);
      if (lane == 0) t2_s[o] = v;
    }
  }
  __syncthreads();
  // mtb[i] = g_w[i].t2 + sg[i]*d1 + g_b[i]*(d2 + 4096*d1)
  {
    const float4 tv = *(const float4*)&t2_s[lane * 4];
    for (int i = wave; i < 128; i += 16) {
      const float4 r = *(const float4*)(g_w + (size_t)i * 256 + lane * 4);
      float v = r.x * tv.x + r.y * tv.y + r.z * tv.z + r.w * tv.w;
      v = wave_reduce(v);
      if (lane == 0)
        mtb_s[i] = v + sgb_s[i] * d1 + gbb_s[i] * (d2 + 4096.0f * d1);
    }
  }
  __syncthreads();
  // bias_out[o] = sc*( (W_w[o].mtb)/4096 - mean ) + beta
  {
    const float2 mv = *(const float2*)&mtb_s[lane * 2];
    for (int o = wave; o < 256; o += 16) {
      const float2 r = *(const float2*)(W_w + (size_t)o * 128 + lane * 2);
      float v = r.x * mv.x + r.y * mv.y;
      v = wave_reduce(v);
      if (lane == 0) {
        const float bias_full = v * (1.0f / 4096.0f);
        const float sc = bn_gamma[o] * rsqrtf(bn_var[o] + BN_EPS);
        bias_out[b * 256 + o] = sc * (bias_full - bn_mean[o]) + bn_beta[o];
      }
    }
  }
}

// ================= T1[b] = Wg @ G[b] (reg-prefetch fp32 tiles) ===================
__global__ __launch_bounds__(256) void chainA_kernel(const float* __restrict__ Wg,
                                                     const float* __restrict__ G,
                                                     float* __restrict__ T1) {
  const int b = blockIdx.z;
  __shared__ float As[16][68], Bs[16][68];
  const int n0 = blockIdx.x * 64, m0 = blockIdx.y * 64;
  const int tx = threadIdx.x, ty = threadIdx.y;
  const int tid = (ty << 4) | tx;
  const float* Gb = G + (size_t)b * 65536;
  float acc[4][4] = {};
  float4 ar = fetch_tr(Wg, 256, m0, 0, tid);
  float4 br = fetch_dir(Gb, 256, 0, n0, tid);
  for (int kt = 0; kt < 16; ++kt) {
    stash_tr(As, ar, tid); stash_dir(Bs, br, tid);
    __syncthreads();
    if (kt < 15) { ar = fetch_tr(Wg, 256, m0, (kt + 1) * 16, tid);
                   br = fetch_dir(Gb, 256, (kt + 1) * 16, n0, tid); }
    mm16(As, Bs, acc, ty, tx);
    __syncthreads();
  }
  store_tile(T1 + (size_t)b * 65536, 256, m0, n0, acc, ty, tx);
}

// ================= W_out[b] (bf16 hi/lo) = scale*((T1@PT + rank1)/N + rank1') ====
__global__ __launch_bounds__(256) void chainB_kernel(
    const float* __restrict__ T1, const float* __restrict__ PT,
    const float* __restrict__ Wgs, const float* __restrict__ sPT,
    const float* __restrict__ wgb, const float* __restrict__ vpt,
    const float* __restrict__ bn_gamma, const float* __restrict__ bn_var,
    __bf16* __restrict__ Whi, __bf16* __restrict__ Wlo) {
  const int b = blockIdx.z;
  __shared__ float As[16][68], Bs[16][68];
  const int n0 = blockIdx.x * 64, m0 = blockIdx.y * 64;
  const int tx = threadIdx.x, ty = threadIdx.y;
  const int tid = (ty << 4) | tx;
  const float* T1b = T1 + (size_t)b * 65536;
  float acc[4][4] = {};
  float4 ar = fetch_tr(T1b, 256, m0, 0, tid);
  float4 br = fetch_dir(PT, 256, 0, n0, tid);
  for (int kt = 0; kt < 16; ++kt) {
    stash_tr(As, ar, tid); stash_dir(Bs, br, tid);
    __syncthreads();
    if (kt < 15) { ar = fetch_tr(T1b, 256, m0, (kt + 1) * 16, tid);
                   br = fetch_dir(PT, 256, (kt + 1) * 16, n0, tid); }
    mm16(As, Bs, acc, ty, tx);
    __syncthreads();
  }
  const float invN = 1.0f / 4096.0f;
#pragma unroll
  for (int i = 0; i < 4; ++i) {
    const int o = m0 + (ty << 2) + i;
    const float sc = bn_gamma[o] * rsqrtf(bn_var[o] + BN_EPS);
    const float wgs_o = Wgs[b * 256 + o];
    const float wgb_o = wgb[o];
    __bf16 h4[4], l4[4];
#pragma unroll
    for (int j = 0; j < 4; ++j) {
      const int c = n0 + (tx << 2) + j;
      const float w = sc * ((acc[i][j] + wgs_o * vpt[c] + wgb_o * sPT[b * 256 + c]) * invN +
                            wgb_o * vpt[c]);
      const __bf16 h = (__bf16)w;
      h4[j] = h;
      l4[j] = (__bf16)(w - (float)h);
    }
    __bf16* dh = Whi + (size_t)b * 65536 + (size_t)o * 256 + n0 + (tx << 2);
    __bf16* dl = Wlo + (size_t)b * 65536 + (size_t)o * 256 + n0 + (tx << 2);
    *(bf16x4*)dh = *(bf16x4*)h4;
    *(bf16x4*)dl = *(bf16x4*)l4;
  }
}

// ================= out[b] = W_out[b] @ a[b] + bias  (MFMA) =======================
__global__ __launch_bounds__(256) void out_mfma_kernel(const __bf16* __restrict__ Whi,
                                                       const __bf16* __restrict__ Wlo,
                                                       const __bf16* __restrict__ at,
                                                       const float* __restrict__ bias_out,
                                                       float* __restrict__ out) {
  const int nt = blockIdx.x, mt = blockIdx.y, b = blockIdx.z;
  const int wave = threadIdx.x >> 6, lane = threadIdx.x & 63;
  const int m = lane & 15, q = lane >> 4;
  const int o = mt * 64 + wave * 16 + m;
  const __bf16* wh = Whi + (size_t)b * 65536 + (size_t)o * 256;
  const __bf16* wl = Wlo + (size_t)b * 65536 + (size_t)o * 256;
  const __bf16* atb = at + (size_t)b * NSP * CCH;
  f32x4 acc[4] = {};
#pragma unroll
  for (int ks = 0; ks < 8; ++ks) {
    const int k = ks * 32 + q * 8;
    const bf16x8 ah = *(const bf16x8*)(wh + k);
    const bf16x8 al = *(const bf16x8*)(wl + k);
#pragma unroll
    for (int t4 = 0; t4 < 4; ++t4) {
      const bf16x8 bh = *(const bf16x8*)(atb + (size_t)(nt * 64 + t4 * 16 + m) * 256 + k);
      acc[t4] = __builtin_amdgcn_mfma_f32_16x16x32_bf16(ah, bh, acc[t4], 0, 0, 0);
      acc[t4] = __builtin_amdgcn_mfma_f32_16x16x32_bf16(al, bh, acc[t4], 0, 0, 0);
    }
  }
  float* ob = out + (size_t)b * CCH * NSP;
#pragma unroll
  for (int r = 0; r < 4; ++r) {
    const int orow = mt * 64 + wave * 16 + q * 4 + r;
    const float bo = bias_out[b * 256 + orow];
#pragma unroll
    for (int t4 = 0; t4 < 4; ++t4)
      ob[(size_t)orow * NSP + nt * 64 + t4 * 16 + m] = acc[t4][r] + bo;
  }
}

extern "C" void kernel_launch(void* const* d_in, const int* in_sizes, int n_in,
                              void* d_out, int out_size, void* d_ws, size_t ws_size,
                              hipStream_t stream) {
  (void)in_sizes; (void)n_in; (void)out_size; (void)ws_size;
  const float* a       = (const float*)d_in[0];
  const float* bI      = (const float*)d_in[1];
  const float* theta_w = (const float*)d_in[2];
  const float* theta_b = (const float*)d_in[3];
  const float* phi_w   = (const float*)d_in[4];
  const float* phi_b   = (const float*)d_in[5];
  const float* g_w     = (const float*)d_in[6];
  const float* g_b     = (const float*)d_in[7];
  const float* W_w     = (const float*)d_in[8];
  const float* bn_gamma= (const float*)d_in[9];
  const float* bn_beta = (const float*)d_in[10];
  const float* bn_mean = (const float*)d_in[11];
  const float* bn_var  = (const float*)d_in[12];
  float* out = (float*)d_out;
  float* ws  = (float*)d_ws;

  // fp32 region (float offsets)
  float* G        = ws;                  // 262144
  float* srow     = ws + 262144;         // 1024
  float* Wg       = ws + 263168;         // 65536
  float* PT       = ws + 328704;         // 65536
  float* T1       = ws + 394240;         // 262144
  float* bias_out = ws + 656384;         // 1024
  float* Wgs      = ws + 657408;         // 1024
  float* sPTv     = ws + 658432;         // 1024
  float* wgb      = ws + 659456;         // 256
  float* vpt      = ws + 659712;         // 256
  float* vb_g     = ws + 659968;         // 256
  float* sg_g     = ws + 660224;         // 512
  float* dvec     = ws + 660736;         // 8
  // bf16 region
  __bf16* bhi = (__bf16*)(ws + 661504);      // 8 MB
  __bf16* blo = (__bf16*)(ws + 2758656);     // 8 MB
  __bf16* Whi = (__bf16*)(ws + 4855808);     // 0.5 MB
  __bf16* Wlo = (__bf16*)(ws + 4986880);     // 0.5 MB (end ~20.5 MB)
  __bf16* at  = bhi;  // alias: bhi dead after gram; cast_a launched after gram

  hipMemsetAsync(G, 0, 263168 * sizeof(float), stream);  // G + srow (atomics)

  setup_kernel<<<dim3(1056), dim3(256), 0, stream>>>(bI, bhi, blo, srow, W_w, g_w, phi_w,
                                                     theta_w, Wg, PT);
  gram_mfma_kernel<<<dim3(4, 4, 32), dim3(256), 0, stream>>>(bhi, blo, G);
  auxA_kernel<<<dim3(5), dim3(1024), 0, stream>>>(srow, W_w, g_w, phi_w, theta_w,
                                                  theta_b, phi_b, g_b,
                                                  Wgs, sPTv, wgb, vpt, vb_g, sg_g, dvec);
  cast_a_kernel<<<dim3(64, 4, 4), dim3(256), 0, stream>>>(a, at);
  chainA_kernel<<<dim3(4, 4, 4), dim3(16, 16), 0, stream>>>(Wg, G, T1);
  auxB_kernel<<<dim3(4), dim3(1024), 0, stream>>>(G, vb_g, sg_g, dvec, g_w, g_b, W_w,
                                                  bn_gamma, bn_beta, bn_mean, bn_var,
                                                  bias_out);
  chainB_kernel<<<dim3(4, 4, 4), dim3(16, 16), 0, stream>>>(T1, PT, Wgs, sPTv, wgb, vpt,
                                                            bn_gamma, bn_var, Whi, Wlo);
  out_mfma_kernel<<<dim3(64, 4, 4), dim3(256), 0, stream>>>(Whi, Wlo, at, bias_out, out);
}